// Round 11
// baseline (298.146 us; speedup 1.0000x reference)
//
#include <hip/hip_runtime.h>
#include <hip/hip_bf16.h>

// RingAttention on MI355X (gfx950). Ring online-softmax merge over S=4 KV
// shards == one flash pass over S*N=8192 keys with rank-0 queries.
// S=4, B=2, N=2048, C=1024, H=16, D=64.
// No-max softmax (scores bounded): p = exp2(s'), log2e/8 folded into q proj.
// R11 changes (glue; R10: v_perm pack banked attn at 135us, merge kernel is
// ~11us of pure fp32 round-trip traffic):
//  - merge_halves FUSED into out-proj (MODE 2) A-staging: reg-prefetch
//    A = f2bf((po0+po1) * 1/l) -> ds_write (bit-identical math to old merge).
//    Per K-iter the 32-col window spans one head-half -> h = it>>1 uniform;
//    l reloaded every 2nd iter only. B-side stays global_load_lds.
//    Deletes merge kernel (72MB traffic) + attn-buffer round trip (16MB).
// Frozen: attn (R10: 512thr/512blk, T15 deferred-PV, v_perm pack, 135us),
// fused qkv GEMM (2304 blocks XCD-pinned), all layouts.

typedef __bf16 bf16x8 __attribute__((ext_vector_type(8)));
typedef float v4f __attribute__((ext_vector_type(4)));

#if __has_builtin(__builtin_amdgcn_exp2f)
#define EXP2F(x) __builtin_amdgcn_exp2f(x)
#else
#define EXP2F(x) exp2f(x)
#endif

__device__ __forceinline__ float bf2f(unsigned short h) {
  union { unsigned int u; float f; } a; a.u = ((unsigned int)h) << 16; return a.f;
}
__device__ __forceinline__ unsigned short f2bf(float f) {
  union { float f; unsigned int u; } a; a.f = f;
  unsigned int u = a.u;
  unsigned int r = (u + 0x7fffu + ((u >> 16) & 1u)) >> 16;  // RNE
  return (unsigned short)r;
}
// truncating pack of two fp32 -> bf16x2 (denominator uses the same bits via
// MFMA). v_perm_b32: D = [b.b3, b.b2, a.b3, a.b2] -> selector 0x07060302.
__device__ __forceinline__ unsigned int pack2t(float a, float b) {
  union { float f; unsigned int u; } ua, ub; ua.f = a; ub.f = b;
#if __has_builtin(__builtin_amdgcn_perm)
  return __builtin_amdgcn_perm(ub.u, ua.u, 0x07060302u);
#else
  return (ua.u >> 16) | (ub.u & 0xffff0000u);
#endif
}
// 16B-aligned fragment load (LDS or global)
__device__ __forceinline__ bf16x8 ldfrag16(const unsigned short* p) {
  union { uint4 u; bf16x8 v; } x; x.u = *(const uint4*)p; return x.v;
}
__device__ __forceinline__ bf16x8 ones8() {
  union { unsigned short s[8]; bf16x8 v; } x;
#pragma unroll
  for (int i = 0; i < 8; i++) x.s[i] = 0x3F80;  // 1.0 bf16
  return x.v;
}
// async global->LDS, 16B per lane; LDS dest = wave-uniform base + lane*16
__device__ __forceinline__ void gld_lds16(const unsigned short* g, unsigned short* l) {
  __builtin_amdgcn_global_load_lds((__attribute__((address_space(1))) void*)g,
                                   (__attribute__((address_space(3))) void*)l, 16, 0, 0);
}

// ---------------- runtime dtype detection ----------------
__global__ void detect_dtype(const unsigned short* __restrict__ x, int* flag) {
  __shared__ int cnt;
  if (threadIdx.x == 0) cnt = 0;
  __syncthreads();
  int sane = 0;
#pragma unroll
  for (int j = 0; j < 4; j++) {
    unsigned short v = x[2 * (threadIdx.x + 64 * j)];
    int e = (v >> 7) & 0xFF;
    if (e >= 90 && e <= 140) sane++;
  }
  atomicAdd(&cnt, sane);
  __syncthreads();
  if (threadIdx.x == 0) *flag = (cnt > 160) ? 0 : 1;  // 1 => fp32 inputs
}

// ---------------- dtype-flag conversion to bf16 (4 elems/thread) ----------------
__global__ void conv_to_bf16(const void* __restrict__ in, unsigned short* __restrict__ out,
                             int n4, const int* __restrict__ flag) {
  int i = blockIdx.x * blockDim.x + threadIdx.x;
  if (i >= n4) return;
  if (*flag) {
    float4 v = ((const float4*)in)[i];
    ushort4 o;
    o.x = f2bf(v.x); o.y = f2bf(v.y); o.z = f2bf(v.z); o.w = f2bf(v.w);
    ((ushort4*)out)[i] = o;
  } else {
    ((ushort4*)out)[i] = ((const ushort4*)in)[i];
  }
}

// ---------------- both biases in one launch (grid 4 x 256) ----------------
__global__ void conv_bias(const void* __restrict__ bq_in, const void* __restrict__ bp_in,
                          unsigned short* __restrict__ bq, unsigned short* __restrict__ bp,
                          const int* __restrict__ flag) {
  int i = blockIdx.x * 256 + threadIdx.x;      // 0..1023 ushort4 slots
  const void* in = (i < 768) ? bq_in : bp_in;
  unsigned short* out = (i < 768) ? bq : bp;
  int j = (i < 768) ? i : i - 768;
  if (*flag) {
    float4 v = ((const float4*)in)[j];
    ushort4 o;
    o.x = f2bf(v.x); o.y = f2bf(v.y); o.z = f2bf(v.z); o.w = f2bf(v.w);
    ((ushort4*)out)[j] = o;
  } else {
    ((ushort4*)out)[j] = ((const ushort4*)in)[j];
  }
}

// ------------- both weight transposes in one launch : out[C][R] = in[R][C] -------------
__global__ void trans_both(const void* __restrict__ wqkv, const void* __restrict__ wproj,
                           unsigned short* __restrict__ wt1, unsigned short* __restrict__ wt2,
                           const int* __restrict__ flag) {
  __shared__ unsigned short t[32][33];
  int tx = threadIdx.x, ty = threadIdx.y;
  int bx = blockIdx.x;
  const void* in; unsigned short* out; int C, c0;
  if (bx < 96) { in = wqkv; out = wt1; C = 3072; c0 = bx * 32; }
  else         { in = wproj; out = wt2; C = 1024; c0 = (bx - 96) * 32; }
  const int R = 1024;
  int r0 = blockIdx.y * 32;
  int fp = *flag;
#pragma unroll
  for (int j = 0; j < 32; j += 8) {
    unsigned short v;
    if (fp) v = f2bf(((const float*)in)[(r0 + ty + j) * C + c0 + tx]);
    else    v = ((const unsigned short*)in)[(r0 + ty + j) * C + c0 + tx];
    t[ty + j][tx] = v;
  }
  __syncthreads();
#pragma unroll
  for (int j = 0; j < 32; j += 8) out[(c0 + ty + j) * R + r0 + tx] = t[tx][ty + j];
}

// --------------------- tiled bf16 GEMM: C = A @ Bt^T + bias ---------------------
// 128x128 tile, BK=32, unpadded LDS; m97 K-loop with global_load_lds width=16.
// MODE 4: fused qkv projection, 1-D grid 2304, XCD-pinned decode:
//   xcd = id&7; t = id>>3 (288/XCD); x = t&7 (fastest); yl = t>>3 (36/XCD);
//   y = xcd*36 + yl in [0,288): y<256 -> pair j=y>>1 (even=k, odd=v, same A
//   rows m0=j*128); y>=256 -> q (m0=(y-256)*128, scaled by log2e/8).
//   v uses the sigma kv' epilogue into vt; k/q write plain bf16.
// MODE 2: out proj with FUSED half-merge: A param = po (fp32 [2][4096][1024]
//   unnormalized halves), Bt2 param = lbuf (fp32 [2][2][16][2048] row sums).
//   A-staging (reg-prefetch): a = f2bf((po0+po1) * 1/(l0+l1)); the 32-col
//   window of iter it spans one head-half -> h = it>>1 uniform; l reloaded
//   every 2nd iter. B stays global_load_lds. 256 blocks, 4 m-tiles/XCD.
template <int MODE>
__launch_bounds__(256, 3)
__global__ void gemm_bt(const unsigned short* __restrict__ A,
                        const unsigned short* __restrict__ Bt,
                        const unsigned short* __restrict__ bias,
                        void* __restrict__ Cout,
                        int K, int ldc, const int* __restrict__ flag,
                        const unsigned short* Bt2, const unsigned short* bias2,
                        void* Cout2,
                        const unsigned short* Bt3, const unsigned short* bias3,
                        void* Cout3) {
  __shared__ unsigned short As[128 * 32];
  __shared__ unsigned short Bs[128 * 32];
  int tid = threadIdx.x;
  int w = tid >> 6, lane = tid & 63, col = lane & 15, quad = lane >> 4;
  int wm = w >> 1, wn = w & 1;
  const unsigned short* Bt_ = Bt;
  const unsigned short* bias_ = bias;
  void* Cout_ = Cout;
  bool isq = false, isv = false;
  int n0, m0;
  if constexpr (MODE == 4) {
    int id = blockIdx.x;                  // 2304 blocks
    int xcd = id & 7, t = id >> 3;        // t in [0,288)
    n0 = (t & 7) * 128;                   // x fastest within XCD
    int y = xcd * 36 + (t >> 3);          // y in [0,288)
    if (y < 256) {
      m0 = (y >> 1) * 128;                // k/v pair shares A rows
      if (y & 1) { isv = true; Bt_ = Bt3; bias_ = bias3; Cout_ = Cout3; }
    } else {
      m0 = (y - 256) * 128;               // q (shard-0 rows)
      isq = true; Bt_ = Bt2; bias_ = bias2; Cout_ = Cout2;
    }
  } else {  // MODE 2: 256 blocks, 32 m-tiles, 4 per XCD
    int id = blockIdx.x;
    int xcd = id & 7, t = id >> 3;        // t in [0,32)
    n0 = (t & 7) * 128;
    m0 = (xcd * 4 + (t >> 3)) * 128;
  }
  int fp = 0;
  if constexpr (MODE == 2) fp = *flag;

  v4f acc[4][4];
#pragma unroll
  for (int i = 0; i < 4; i++)
#pragma unroll
    for (int j = 0; j < 4; j++) acc[i][j] = v4f{0.f, 0.f, 0.f, 0.f};

  // staging: lane i of wave w covers slot 64w+i (rows 16w..16w+15) and slot +256
  int ra0 = tid >> 2, cc = tid & 3;            // ra0 in [0,64), cc in [0,4)
  const unsigned short* ga0 = &A[(m0 + ra0) * K + cc * 8];
  const unsigned short* ga1 = ga0 + 64 * K;
  const unsigned short* gb0 = &Bt_[(n0 + ra0) * K + cc * 8];
  const unsigned short* gb1 = gb0 + 64 * K;
  unsigned short* lA0 = &As[(w * 16) * 32];          // wave-uniform LDS bases
  unsigned short* lA1 = &As[(64 + w * 16) * 32];
  unsigned short* lB0 = &Bs[(w * 16) * 32];
  unsigned short* lB1 = &Bs[(64 + w * 16) * 32];

  // MODE 2 fused-merge staging state
  const float* poA = (const float*)A;          // halves: +0 / +4194304 floats
  const float* lb  = (const float*)Bt2;        // [2][2][16][2048]
  const float* pa0 = &poA[(m0 + ra0) * 1024 + cc * 8];
  const float* pa1 = pa0 + 64 * 1024;
  int r0g = m0 + ra0, r1g = r0g + 64;
  int lbi0 = ((r0g >> 11) * 16) * 2048 + (r0g & 2047);
  int lbi1 = ((r1g >> 11) * 16) * 2048 + (r1g & 2047);
  unsigned short* da0 = &As[ra0 * 32 + cc * 8];
  unsigned short* da1 = da0 + 64 * 32;
  float inv0 = 0.f, inv1 = 0.f;
  uint4 wA0, wA1;

#define PREP_A2(IT)                                                            \
  {                                                                            \
    if (!((IT) & 1)) {                                                         \
      int ho = ((IT) >> 1) * 2048;                                             \
      inv0 = 1.f / (lb[lbi0 + ho] + lb[65536 + lbi0 + ho]);                    \
      inv1 = 1.f / (lb[lbi1 + ho] + lb[65536 + lbi1 + ho]);                    \
    }                                                                          \
    const float* p0 = pa0 + (IT) * 32;                                         \
    const float* p1 = pa1 + (IT) * 32;                                         \
    float4 x0 = *(const float4*)p0, x1 = *(const float4*)(p0 + 4);             \
    float4 y0 = *(const float4*)(p0 + 4194304), y1 = *(const float4*)(p0 + 4194304 + 4); \
    float4 x2 = *(const float4*)p1, x3 = *(const float4*)(p1 + 4);             \
    float4 y2 = *(const float4*)(p1 + 4194304), y3 = *(const float4*)(p1 + 4194304 + 4); \
    union { unsigned short s[8]; uint4 q; } u0, u1;                            \
    u0.s[0] = f2bf((x0.x + y0.x) * inv0); u0.s[1] = f2bf((x0.y + y0.y) * inv0);\
    u0.s[2] = f2bf((x0.z + y0.z) * inv0); u0.s[3] = f2bf((x0.w + y0.w) * inv0);\
    u0.s[4] = f2bf((x1.x + y1.x) * inv0); u0.s[5] = f2bf((x1.y + y1.y) * inv0);\
    u0.s[6] = f2bf((x1.z + y1.z) * inv0); u0.s[7] = f2bf((x1.w + y1.w) * inv0);\
    u1.s[0] = f2bf((x2.x + y2.x) * inv1); u1.s[1] = f2bf((x2.y + y2.y) * inv1);\
    u1.s[2] = f2bf((x2.z + y2.z) * inv1); u1.s[3] = f2bf((x2.w + y2.w) * inv1);\
    u1.s[4] = f2bf((x3.x + y3.x) * inv1); u1.s[5] = f2bf((x3.y + y3.y) * inv1);\
    u1.s[6] = f2bf((x3.z + y3.z) * inv1); u1.s[7] = f2bf((x3.w + y3.w) * inv1);\
    wA0 = u0.q; wA1 = u1.q;                                                    \
  }

  if constexpr (MODE == 2) { PREP_A2(0); }

  int niter = K >> 5;
  for (int it = 0; it < niter; it++) {
    __syncthreads();                     // prev compute done; LDS writable
    if constexpr (MODE == 2) {
      *(uint4*)da0 = wA0; *(uint4*)da1 = wA1;   // merged A tile (prepped prev iter)
      gld_lds16(gb0, lB0); gld_lds16(gb1, lB1);
      gb0 += 32; gb1 += 32;
      if (it + 1 < niter) { PREP_A2(it + 1); }  // prefetch flies during compute
    } else {
      gld_lds16(ga0, lA0); gld_lds16(ga1, lA1);
      gld_lds16(gb0, lB0); gld_lds16(gb1, lB1);
      ga0 += 32; ga1 += 32; gb0 += 32; gb1 += 32;
    }
    __syncthreads();                     // staging drained -> tile ready
    bf16x8 af[4], bfr[4];
#pragma unroll
    for (int mi = 0; mi < 4; mi++) af[mi] = ldfrag16(&As[(wm * 64 + mi * 16 + col) * 32 + quad * 8]);
#pragma unroll
    for (int ni = 0; ni < 4; ni++) bfr[ni] = ldfrag16(&Bs[(wn * 64 + ni * 16 + col) * 32 + quad * 8]);
#pragma unroll
    for (int mi = 0; mi < 4; mi++)
#pragma unroll
      for (int ni = 0; ni < 4; ni++)
        acc[mi][ni] = __builtin_amdgcn_mfma_f32_16x16x32_bf16(af[mi], bfr[ni], acc[mi][ni], 0, 0, 0);
  }
#undef PREP_A2

  float bv[4];
#pragma unroll
  for (int ni = 0; ni < 4; ni++) bv[ni] = bf2f(bias_[n0 + wn * 64 + ni * 16 + col]);

  if (MODE == 4 && isv) {
    // packed V store: rows m0+wm*64..+63 form one 64-kv block;
    // kv' = (mi&1)*32 + quad*8 + 2r + (mi>>1): two ushort2 per (ni,r)
    int rgb0 = m0 + wm * 64;
    int s = rgb0 >> 12, b = (rgb0 >> 11) & 1, n = rgb0 & 2047;
    int kvg0 = s * 2048 + n;               // 64-aligned
#pragma unroll
    for (int ni = 0; ni < 4; ni++) {
      int cg = n0 + wn * 64 + ni * 16 + col;
      int h = cg >> 6, d = cg & 63;
      unsigned short* rowp = &((unsigned short*)Cout_)[((b * 16 + h) * 64 + d) * 8192 + kvg0];
      float bvn = bv[ni];
#pragma unroll
      for (int r = 0; r < 4; r++) {
        ushort2 e, o2;
        e.x = f2bf(acc[0][ni][r] + bvn);   // mi=0 -> kv' = quad*8 + 2r
        e.y = f2bf(acc[2][ni][r] + bvn);   // mi=2 -> kv' = quad*8 + 2r + 1
        o2.x = f2bf(acc[1][ni][r] + bvn);  // mi=1 -> kv' = 32 + quad*8 + 2r
        o2.y = f2bf(acc[3][ni][r] + bvn);  // mi=3 -> kv' = 32 + quad*8 + 2r + 1
        *(ushort2*)&rowp[2 * (quad * 4 + r)] = e;
        *(ushort2*)&rowp[32 + 2 * (quad * 4 + r)] = o2;
      }
    }
  } else {
#pragma unroll
    for (int mi = 0; mi < 4; mi++)
#pragma unroll
      for (int ni = 0; ni < 4; ni++) {
        float vals[4];
#pragma unroll
        for (int r = 0; r < 4; r++) vals[r] = acc[mi][ni][r] + bv[ni];
        if constexpr (MODE == 4) {
          if (isq) {
#pragma unroll
            for (int r = 0; r < 4; r++) vals[r] *= 0.1803368801111601f;  // log2e/8
          }
        }
        int rgb = m0 + wm * 64 + mi * 16 + quad * 4;          // base row (+r)
        int cg  = n0 + wn * 64 + ni * 16 + col;               // col
        if constexpr (MODE == 4) {
          unsigned short* C = (unsigned short*)Cout_;
#pragma unroll
          for (int r = 0; r < 4; r++) C[(rgb + r) * ldc + cg] = f2bf(vals[r]);
        } else {
          if (fp) {
            float* C = (float*)Cout_;
#pragma unroll
            for (int r = 0; r < 4; r++) C[(rgb + r) * ldc + cg] = vals[r];
          } else {
            unsigned short* C = (unsigned short*)Cout_;
#pragma unroll
            for (int r = 0; r < 4; r++) C[(rgb + r) * ldc + cg] = f2bf(vals[r]);
          }
        }
      }
  }
}

// ----------------------------- flash attention -----------------------------
// Grid: 1-D 512 blocks (8 qtiles x 32 bh x 2 halves), 512 threads (8 waves),
// XCD-pinned decode. LDS: K dbuf (16K) + V tribuf (24K) = 40 KiB, 2 blocks/CU.
// T15 deferred-PV pipeline, one barrier per kv-tile:
//   iter t: QK(t) [MFMA] -> { PV(t-1) [MFMA, independent] || exp(t)+pack(t)
//   [VALU] } -> stage(t+1) -> barrier.
// V(t-1) lives in the third V buffer while tile t+1 is staged. aP carried in
// registers across the barrier. Swapped QK^T: lane owns P[q=col][16 kv], packs
// in-register to PV A-fragments (sigma kv' layout matches vt permutation).
// Staging lane-map (512 thr: r0=tid>>3, c0=tid&7): every 8-lane issue group
// covers a full 8-slot XOR permutation = 32 banks (R9 lesson).
// Writes UNNORMALIZED fp32 O-partials + l to workspace; out-proj merges.
__launch_bounds__(512, 4)
__global__ void attn_kernel(const unsigned short* __restrict__ qbuf,   // [4096,1024]
                            const unsigned short* __restrict__ kbuf,   // [16384,1024]
                            const unsigned short* __restrict__ vt,     // [32*64, 8192] kv-permuted
                            float* __restrict__ po,                    // [2][4096][1024] fp32
                            float* __restrict__ lbuf) {                // [2][2][16][2048]
  __shared__ unsigned short Ks[2][64 * 64];    // double-buffered, swizzled [kv][d]
  __shared__ unsigned short Vs[3][64 * 64];    // TRIPLE-buffered, swizzled [d][kv']
  int tid = threadIdx.x;
  int w = tid >> 6, lane = tid & 63, col = lane & 15, quad = lane >> 4;
  // XCD-pinned decode: xcd = id%8; slot = id/8; qt = slot%8; group = (slot/8)*8+xcd
  int id = blockIdx.x;
  int xcd = id & 7, slot = id >> 3;
  int qt = slot & 7, gsub = slot >> 3;
  int g = gsub * 8 + xcd;                      // 0..63 (bh,half) group
  int bh = g >> 1, half = g & 1;
  int b = bh >> 4, h = bh & 15;
  int q0 = qt * 256;

  // Q fragments direct from global (B-operand: lane holds
  // Q[q = mj*16+col][d = kk*32 + quad*8 .. +7], one contiguous 16B read)
  bf16x8 aQ[2][2];
#pragma unroll
  for (int mj = 0; mj < 2; mj++)
#pragma unroll
    for (int kk = 0; kk < 2; kk++)
      aQ[mj][kk] = ldfrag16(&qbuf[(b * 2048 + q0 + w * 32 + mj * 16 + col) * 1024 +
                                  h * 64 + kk * 32 + quad * 8]);

  // K/V staging: 512 threads cover one 64x64 tile, one uint4 each
  int r0 = tid >> 3, c0 = tid & 7;             // r0 in [0,64), c0 in [0,8)
  const unsigned short* kp = &kbuf[((half * 2) * 4096 + b * 2048 + r0) * 1024 + h * 64 + c0 * 8];
  const unsigned short* vp = &vt[(bh * 64 + r0) * 8192 + half * 4096 + c0 * 8];
  int sdst = r0 * 64 + 8 * (c0 ^ (r0 & 7));    // swizzled LDS slot (shorts)

  const bf16x8 vone = ones8();
  v4f o[2][4];
  v4f acc_l[2] = {v4f{0.f, 0.f, 0.f, 0.f}, v4f{0.f, 0.f, 0.f, 0.f}};
#pragma unroll
  for (int mj = 0; mj < 2; mj++)
#pragma unroll
    for (int di = 0; di < 4; di++) o[mj][di] = v4f{0.f, 0.f, 0.f, 0.f};

  // ---- prologue: stage tile 0; prefetch tile 1; QK(0)+exp+pack; stage tile 1
  {
    uint4 k0 = *(const uint4*)kp, v0 = *(const uint4*)vp;
    *(uint4*)&Ks[0][sdst] = k0;
    *(uint4*)&Vs[0][sdst] = v0;
  }
  kp += 64 * 1024; vp += 64;                   // tile 1 (no shard crossing at t=1)
  uint4 pk = *(const uint4*)kp, pv = *(const uint4*)vp;
  __syncthreads();

  bf16x8 aP[2][2];
  {
    v4f sc[4][2];
#pragma unroll
    for (int ni = 0; ni < 4; ni++)
#pragma unroll
      for (int mj = 0; mj < 2; mj++) sc[ni][mj] = v4f{0.f, 0.f, 0.f, 0.f};
#pragma unroll
    for (int kk = 0; kk < 2; kk++) {
      bf16x8 aK[4];
#pragma unroll
      for (int ni = 0; ni < 4; ni++) {
        int row = ni * 16 + col;
        aK[ni] = ldfrag16(&Ks[0][row * 64 + 8 * ((kk * 4 + quad) ^ (col & 7))]);
      }
#pragma unroll
      for (int ni = 0; ni < 4; ni++)
#pragma unroll
        for (int mj = 0; mj < 2; mj++)
          sc[ni][mj] = __builtin_amdgcn_mfma_f32_16x16x32_bf16(aK[ni], aQ[mj][kk], sc[ni][mj], 0, 0, 0);
    }
#pragma unroll
    for (int ni = 0; ni < 4; ni++)
#pragma unroll
      for (int mj = 0; mj < 2; mj++)
#pragma unroll
        for (int r = 0; r < 4; r++) sc[ni][mj][r] = EXP2F(sc[ni][mj][r]);
#pragma unroll
    for (int mj = 0; mj < 2; mj++)
#pragma unroll
      for (int kk = 0; kk < 2; kk++) {
        union { unsigned int d[4]; bf16x8 v; } u;
#pragma unroll
        for (int t = 0; t < 4; t++)
          u.d[t] = pack2t(sc[kk][mj][t], sc[kk + 2][mj][t]);
        aP[mj][kk] = u.v;
      }
  }
  // stage tile 1 (pk/pv arrived during QK(0) compute)
  *(uint4*)&Ks[1][sdst] = pk;
  *(uint4*)&Vs[1][sdst] = pv;
  __syncthreads();

  const unsigned short* vprev = Vs[0];
  const unsigned short* vcur  = Vs[1];
  const unsigned short* vnext = Vs[2];

  // ---- main loop: t = 1..63; PV(t-1) deferred into iter t
  for (int t = 1; t < 64; t++) {
    const unsigned short* kcur = Ks[t & 1];
    unsigned short* knxt = (unsigned short*)Ks[(t + 1) & 1];
    if (t < 63) {   // prefetch tile t+1 (uniform branch)
      int kstep = (((t + 1) & 31) == 0) ? (2048 + 64) * 1024 : 64 * 1024;
      kp += kstep; vp += 64;
      pk = *(const uint4*)kp; pv = *(const uint4*)vp;
    }

    // QK(t): 16 MFMA -> sc
    v4f sc[4][2];
#pragma unroll
    for (int ni = 0; ni < 4; ni++)
#pragma unroll
      for (int mj = 0; mj < 2; mj++) sc[ni][mj] = v4f{0.f, 0.f, 0.f, 0.f};
#pragma unroll
    for (int kk = 0; kk < 2; kk++) {
      bf16x8 aK[4];
#pragma unroll
      for (int ni = 0; ni < 4; ni++) {
        int row = ni * 16 + col;
        aK[ni] = ldfrag16(&kcur[row * 64 + 8 * ((kk * 4 + quad) ^ (col & 7))]);
      }
#pragma unroll
      for (int ni = 0; ni < 4; ni++)
#pragma unroll
        for (int mj = 0; mj < 2; mj++)
          sc[ni][mj] = __builtin_amdgcn_mfma_f32_16x16x32_bf16(aK[ni], aQ[mj][kk], sc[ni][mj], 0, 0, 0);
    }

    // PV(t-1): 20 MFMA on (aP, vprev) — independent of sc/exp below;
    // compiler interleaves these MFMAs with the exp/pack VALU cluster.
#pragma unroll
    for (int kk = 0; kk < 2; kk++) {
#pragma unroll
      for (int mj = 0; mj < 2; mj++)
        acc_l[mj] = __builtin_amdgcn_mfma_f32_16x16x32_bf16(aP[mj][kk], vone, acc_l[mj], 0, 0, 0);
      bf16x8 bV[4];
#pragma unroll
      for (int di = 0; di < 4; di++) {
        int row = di * 16 + col;
        bV[di] = ldfrag16(&vprev[row * 64 + 8 * ((kk * 4 + quad) ^ (col & 7))]);
      }
#pragma unroll
      for (int mj = 0; mj < 2; mj++)
#pragma unroll
        for (int di = 0; di < 4; di++)
          o[mj][di] = __builtin_amdgcn_mfma_f32_16x16x32_bf16(aP[mj][kk], bV[di], o[mj][di], 0, 0, 0);
    }

    // exp(t) + pack(t) -> new aP (VALU; overlaps PV(t-1) MFMAs above)
#pragma unroll
    for (int ni = 0; ni < 4; ni++)
#pragma unroll
      for (int mj = 0; mj < 2; mj++)
#pragma unroll
        for (int r = 0; r < 4; r++) sc[ni][mj][r] = EXP2F(sc[ni][mj][r]);
    bf16x8 aPn[2][2];
#pragma unroll
    for (int mj = 0; mj < 2; mj++)
#pragma unroll
      for (int kk = 0; kk < 2; kk++) {
        union { unsigned int d[4]; bf16x8 v; } u;
#pragma unroll
        for (int tt = 0; tt < 4; tt++)
          u.d[tt] = pack2t(sc[kk][mj][tt], sc[kk + 2][mj][tt]);
        aPn[mj][kk] = u.v;
      }

    // stage tile t+1 (K -> alt K buf; V -> vnext, distinct from vprev/vcur)
    if (t < 63) {
      *(uint4*)&knxt[sdst] = pk;
      *(uint4*)&((unsigned short*)vnext)[sdst] = pv;
    }

    __syncthreads();   // tile t+1 visible; everyone done with Ks[t&1], vprev

    // carry aP; rotate V buffers
#pragma unroll
    for (int mj = 0; mj < 2; mj++)
#pragma unroll
      for (int kk = 0; kk < 2; kk++) aP[mj][kk] = aPn[mj][kk];
    const unsigned short* vt_ = vprev;
    vprev = vcur; vcur = vnext; vnext = vt_;
  }

  // ---- epilogue: PV(63) (vprev now holds V(63))
#pragma unroll
  for (int kk = 0; kk < 2; kk++) {
#pragma unroll
    for (int mj = 0; mj < 2; mj++)
      acc_l[mj] = __builtin_amdgcn_mfma_f32_16x16x32_bf16(aP[mj][kk], vone, acc_l[mj], 0, 0, 0);
    bf16x8 bV[4];
#pragma unroll
    for (int di = 0; di < 4; di++) {
      int row = di * 16 + col;
      bV[di] = ldfrag16(&vprev[row * 64 + 8 * ((kk * 4 + quad) ^ (col & 7))]);
    }
#pragma unroll
    for (int mj = 0; mj < 2; mj++)
#pragma unroll
      for (int di = 0; di < 4; di++)
        o[mj][di] = __builtin_amdgcn_mfma_f32_16x16x32_bf16(aP[mj][kk], bV[di], o[mj][di], 0, 0, 0);
  }

  // write unnormalized fp32 partials + row sums (out-proj merges/normalizes)
  float* pb = po + half * 4194304;
#pragma unroll
  for (int mj = 0; mj < 2; mj++)
#pragma unroll
    for (int r = 0; r < 4; r++) {
      int n = q0 + w * 32 + mj * 16 + quad * 4 + r;
      if (col == 0) lbuf[half * 65536 + (b * 16 + h) * 2048 + n] = acc_l[mj][r];
#pragma unroll
      for (int di = 0; di < 4; di++) {
        int c = h * 64 + di * 16 + col;
        pb[(b * 2048 + n) * 1024 + c] = o[mj][di][r];
      }
    }
}

extern "C" void kernel_launch(void* const* d_in, const int* in_sizes, int n_in,
                              void* d_out, int out_size, void* d_ws, size_t ws_size,
                              hipStream_t stream) {
  const void* x      = d_in[0];  // [4,2,2048,1024]
  const void* w_qkv  = d_in[1];  // [1024,3072]
  const void* b_qkv  = d_in[2];  // [3072]
  const void* w_proj = d_in[3];  // [1024,1024]
  const void* b_proj = d_in[4];  // [1024]

  char* ws = (char*)d_ws;
  unsigned short* xb   = (unsigned short*)(ws);                // 33,554,432 B
  unsigned short* kk   = (unsigned short*)(ws + 33554432);     // 33,554,432 B
  unsigned short* vt   = (unsigned short*)(ws + 67108864);     // 33,554,432 B
  unsigned short* q0b  = (unsigned short*)(ws + 100663296);    //  8,388,608 B
  unsigned short* wt1  = (unsigned short*)(ws + 117440512);    //  6,291,456 B
  unsigned short* wt2  = (unsigned short*)(ws + 123731968);    //  2,097,152 B
  unsigned short* bq   = (unsigned short*)(ws + 125829120);    //      6,144 B
  unsigned short* bp   = (unsigned short*)(ws + 125835264);    //      2,048 B
  int* flag            = (int*)(ws + 125837312);               //          4 B
  // aliased regions (dead by the time they're reused):
  float* po   = (float*)xb;        // 2 x 16.78 MB fp32 O-partials (xb dead after GEMMs)
  float* lbuf = (float*)wt1;       // 2 x 256 KB row sums (wt1 dead after GEMMs)

  detect_dtype<<<1, 64, 0, stream>>>((const unsigned short*)x, flag);

  conv_to_bf16<<<16384, 256, 0, stream>>>(x, xb, 4194304, flag);
  conv_bias<<<4, 256, 0, stream>>>(b_qkv, b_proj, bq, bp, flag);
  trans_both<<<dim3(128, 32), dim3(32, 8), 0, stream>>>(w_qkv, w_proj, wt1, wt2, flag);

  // ONE fused k+q+v projection launch: 2304 blocks = 3.0 rounds at 3/CU,
  // XCD-pinned so A-panel sharers are consecutive on one XCD.
  gemm_bt<4><<<2304, 256, 0, stream>>>(xb, wt1 + 1024 * 1024, bq + 1024, kk,
                                       1024, 1024, flag,
                                       wt1, bq, q0b,
                                       wt1 + 2048 * 1024, bq + 2048, vt);

  // flash attention: 512 blocks x 512 threads (2 blocks/CU), XCD-pinned,
  // deferred-PV pipeline; writes unnormalized partials + row sums
  attn_kernel<<<512, 512, 0, stream>>>(q0b, kk, vt, po, lbuf);

  // output projection with FUSED half-merge/normalize in A-staging
  // (A = po fp32 halves, Bt2 = lbuf row sums); XCD-pinned 1-D grid
  gemm_bt<2><<<256, 256, 0, stream>>>((const unsigned short*)po, wt2, bp, d_out,
                                      1024, 1024, flag,
                                      (const unsigned short*)lbuf, nullptr, nullptr,
                                      nullptr, nullptr, nullptr);
}

// Round 12
// 287.112 us; speedup vs baseline: 1.0384x; 1.0384x over previous
//
#include <hip/hip_runtime.h>
#include <hip/hip_bf16.h>

// RingAttention on MI355X (gfx950). Ring online-softmax merge over S=4 KV
// shards == one flash pass over S*N=8192 keys with rank-0 queries.
// S=4, B=2, N=2048, C=1024, H=16, D=64.
// No-max softmax (scores bounded): p = exp2(s'), log2e/8 folded into q proj.
// R12: REVERT to R10 (287.4us measured best). R11's merge-into-outproj fusion
// regressed +11us: merge work moved from a 4096-block BW-saturating kernel
// into a 1-block/CU GEMM's staging path -> fp32 half-reads unhidden. Lesson:
// fuse streaming traffic only into high-TLP consumers.
// Components (all counter-verified): attn 135us (512thr/512blk 2/CU, T15
// deferred-PV, swapped QK^T, in-reg P pack via v_perm, XOR swizzle, XCD pin);
// fused qkv GEMM (2304 blk = 3.0 rounds, XCD-pinned A-panel locality);
// separate merge; out-proj XCD-pinned.

typedef __bf16 bf16x8 __attribute__((ext_vector_type(8)));
typedef float v4f __attribute__((ext_vector_type(4)));

#if __has_builtin(__builtin_amdgcn_exp2f)
#define EXP2F(x) __builtin_amdgcn_exp2f(x)
#else
#define EXP2F(x) exp2f(x)
#endif

__device__ __forceinline__ float bf2f(unsigned short h) {
  union { unsigned int u; float f; } a; a.u = ((unsigned int)h) << 16; return a.f;
}
__device__ __forceinline__ unsigned short f2bf(float f) {
  union { float f; unsigned int u; } a; a.f = f;
  unsigned int u = a.u;
  unsigned int r = (u + 0x7fffu + ((u >> 16) & 1u)) >> 16;  // RNE
  return (unsigned short)r;
}
// truncating pack of two fp32 -> bf16x2 (denominator uses the same bits via
// MFMA). v_perm_b32: D = [b.b3, b.b2, a.b3, a.b2] -> selector 0x07060302.
__device__ __forceinline__ unsigned int pack2t(float a, float b) {
  union { float f; unsigned int u; } ua, ub; ua.f = a; ub.f = b;
#if __has_builtin(__builtin_amdgcn_perm)
  return __builtin_amdgcn_perm(ub.u, ua.u, 0x07060302u);
#else
  return (ua.u >> 16) | (ub.u & 0xffff0000u);
#endif
}
// 16B-aligned fragment load (LDS or global)
__device__ __forceinline__ bf16x8 ldfrag16(const unsigned short* p) {
  union { uint4 u; bf16x8 v; } x; x.u = *(const uint4*)p; return x.v;
}
__device__ __forceinline__ bf16x8 ones8() {
  union { unsigned short s[8]; bf16x8 v; } x;
#pragma unroll
  for (int i = 0; i < 8; i++) x.s[i] = 0x3F80;  // 1.0 bf16
  return x.v;
}
// async global->LDS, 16B per lane; LDS dest = wave-uniform base + lane*16
__device__ __forceinline__ void gld_lds16(const unsigned short* g, unsigned short* l) {
  __builtin_amdgcn_global_load_lds((__attribute__((address_space(1))) void*)g,
                                   (__attribute__((address_space(3))) void*)l, 16, 0, 0);
}

// ---------------- runtime dtype detection ----------------
__global__ void detect_dtype(const unsigned short* __restrict__ x, int* flag) {
  __shared__ int cnt;
  if (threadIdx.x == 0) cnt = 0;
  __syncthreads();
  int sane = 0;
#pragma unroll
  for (int j = 0; j < 4; j++) {
    unsigned short v = x[2 * (threadIdx.x + 64 * j)];
    int e = (v >> 7) & 0xFF;
    if (e >= 90 && e <= 140) sane++;
  }
  atomicAdd(&cnt, sane);
  __syncthreads();
  if (threadIdx.x == 0) *flag = (cnt > 160) ? 0 : 1;  // 1 => fp32 inputs
}

// ---------------- dtype-flag conversion to bf16 (4 elems/thread) ----------------
__global__ void conv_to_bf16(const void* __restrict__ in, unsigned short* __restrict__ out,
                             int n4, const int* __restrict__ flag) {
  int i = blockIdx.x * blockDim.x + threadIdx.x;
  if (i >= n4) return;
  if (*flag) {
    float4 v = ((const float4*)in)[i];
    ushort4 o;
    o.x = f2bf(v.x); o.y = f2bf(v.y); o.z = f2bf(v.z); o.w = f2bf(v.w);
    ((ushort4*)out)[i] = o;
  } else {
    ((ushort4*)out)[i] = ((const ushort4*)in)[i];
  }
}

// ---------------- both biases in one launch (grid 4 x 256) ----------------
__global__ void conv_bias(const void* __restrict__ bq_in, const void* __restrict__ bp_in,
                          unsigned short* __restrict__ bq, unsigned short* __restrict__ bp,
                          const int* __restrict__ flag) {
  int i = blockIdx.x * 256 + threadIdx.x;      // 0..1023 ushort4 slots
  const void* in = (i < 768) ? bq_in : bp_in;
  unsigned short* out = (i < 768) ? bq : bp;
  int j = (i < 768) ? i : i - 768;
  if (*flag) {
    float4 v = ((const float4*)in)[j];
    ushort4 o;
    o.x = f2bf(v.x); o.y = f2bf(v.y); o.z = f2bf(v.z); o.w = f2bf(v.w);
    ((ushort4*)out)[j] = o;
  } else {
    ((ushort4*)out)[j] = ((const ushort4*)in)[j];
  }
}

// ------------- both weight transposes in one launch : out[C][R] = in[R][C] -------------
__global__ void trans_both(const void* __restrict__ wqkv, const void* __restrict__ wproj,
                           unsigned short* __restrict__ wt1, unsigned short* __restrict__ wt2,
                           const int* __restrict__ flag) {
  __shared__ unsigned short t[32][33];
  int tx = threadIdx.x, ty = threadIdx.y;
  int bx = blockIdx.x;
  const void* in; unsigned short* out; int C, c0;
  if (bx < 96) { in = wqkv; out = wt1; C = 3072; c0 = bx * 32; }
  else         { in = wproj; out = wt2; C = 1024; c0 = (bx - 96) * 32; }
  const int R = 1024;
  int r0 = blockIdx.y * 32;
  int fp = *flag;
#pragma unroll
  for (int j = 0; j < 32; j += 8) {
    unsigned short v;
    if (fp) v = f2bf(((const float*)in)[(r0 + ty + j) * C + c0 + tx]);
    else    v = ((const unsigned short*)in)[(r0 + ty + j) * C + c0 + tx];
    t[ty + j][tx] = v;
  }
  __syncthreads();
#pragma unroll
  for (int j = 0; j < 32; j += 8) out[(c0 + ty + j) * R + r0 + tx] = t[tx][ty + j];
}

// --------------------- tiled bf16 GEMM: C = A @ Bt^T + bias ---------------------
// 128x128 tile, BK=32, unpadded LDS; m97 K-loop with global_load_lds width=16.
// MODE 4: fused qkv projection, 1-D grid 2304, XCD-pinned decode:
//   xcd = id&7; t = id>>3 (288/XCD); x = t&7 (fastest); yl = t>>3 (36/XCD);
//   y = xcd*36 + yl in [0,288): y<256 -> pair j=y>>1 (even=k, odd=v, same A
//   rows m0=j*128); y>=256 -> q (m0=(y-256)*128, scaled by log2e/8).
//   v uses the sigma kv' epilogue into vt; k/q write plain bf16.
// MODE 2: final output proj (fp32/bf16 per *flag), 1-D grid 256, same swizzle.
template <int MODE>
__launch_bounds__(256, 3)
__global__ void gemm_bt(const unsigned short* __restrict__ A,
                        const unsigned short* __restrict__ Bt,
                        const unsigned short* __restrict__ bias,
                        void* __restrict__ Cout,
                        int K, int ldc, const int* __restrict__ flag,
                        const unsigned short* Bt2, const unsigned short* bias2,
                        void* Cout2,
                        const unsigned short* Bt3, const unsigned short* bias3,
                        void* Cout3) {
  __shared__ unsigned short As[128 * 32];
  __shared__ unsigned short Bs[128 * 32];
  int tid = threadIdx.x;
  int w = tid >> 6, lane = tid & 63, col = lane & 15, quad = lane >> 4;
  int wm = w >> 1, wn = w & 1;
  const unsigned short* Bt_ = Bt;
  const unsigned short* bias_ = bias;
  void* Cout_ = Cout;
  bool isq = false, isv = false;
  int n0, m0;
  if constexpr (MODE == 4) {
    int id = blockIdx.x;                  // 2304 blocks
    int xcd = id & 7, t = id >> 3;        // t in [0,288)
    n0 = (t & 7) * 128;                   // x fastest within XCD
    int y = xcd * 36 + (t >> 3);          // y in [0,288)
    if (y < 256) {
      m0 = (y >> 1) * 128;                // k/v pair shares A rows
      if (y & 1) { isv = true; Bt_ = Bt3; bias_ = bias3; Cout_ = Cout3; }
    } else {
      m0 = (y - 256) * 128;               // q (shard-0 rows)
      isq = true; Bt_ = Bt2; bias_ = bias2; Cout_ = Cout2;
    }
  } else {  // MODE 2: 256 blocks, 32 m-tiles, 4 per XCD
    int id = blockIdx.x;
    int xcd = id & 7, t = id >> 3;        // t in [0,32)
    n0 = (t & 7) * 128;
    m0 = (xcd * 4 + (t >> 3)) * 128;
  }
  int fp = 0;
  if constexpr (MODE == 2) fp = *flag;

  v4f acc[4][4];
#pragma unroll
  for (int i = 0; i < 4; i++)
#pragma unroll
    for (int j = 0; j < 4; j++) acc[i][j] = v4f{0.f, 0.f, 0.f, 0.f};

  // staging: lane i of wave w covers slot 64w+i (rows 16w..16w+15) and slot +256
  int ra0 = tid >> 2, cc = tid & 3;            // ra0 in [0,64), cc in [0,4)
  const unsigned short* ga0 = &A[(m0 + ra0) * K + cc * 8];
  const unsigned short* ga1 = ga0 + 64 * K;
  const unsigned short* gb0 = &Bt_[(n0 + ra0) * K + cc * 8];
  const unsigned short* gb1 = gb0 + 64 * K;
  unsigned short* lA0 = &As[(w * 16) * 32];          // wave-uniform LDS bases
  unsigned short* lA1 = &As[(64 + w * 16) * 32];
  unsigned short* lB0 = &Bs[(w * 16) * 32];
  unsigned short* lB1 = &Bs[(64 + w * 16) * 32];

  int niter = K >> 5;
  for (int it = 0; it < niter; it++) {
    __syncthreads();                     // prev compute done; LDS writable
    gld_lds16(ga0, lA0); gld_lds16(ga1, lA1);
    gld_lds16(gb0, lB0); gld_lds16(gb1, lB1);
    ga0 += 32; ga1 += 32; gb0 += 32; gb1 += 32;
    __syncthreads();                     // vmcnt drained by compiler -> tile ready
    bf16x8 af[4], bfr[4];
#pragma unroll
    for (int mi = 0; mi < 4; mi++) af[mi] = ldfrag16(&As[(wm * 64 + mi * 16 + col) * 32 + quad * 8]);
#pragma unroll
    for (int ni = 0; ni < 4; ni++) bfr[ni] = ldfrag16(&Bs[(wn * 64 + ni * 16 + col) * 32 + quad * 8]);
#pragma unroll
    for (int mi = 0; mi < 4; mi++)
#pragma unroll
      for (int ni = 0; ni < 4; ni++)
        acc[mi][ni] = __builtin_amdgcn_mfma_f32_16x16x32_bf16(af[mi], bfr[ni], acc[mi][ni], 0, 0, 0);
  }

  float bv[4];
#pragma unroll
  for (int ni = 0; ni < 4; ni++) bv[ni] = bf2f(bias_[n0 + wn * 64 + ni * 16 + col]);

  if (MODE == 4 && isv) {
    // packed V store: rows m0+wm*64..+63 form one 64-kv block;
    // kv' = (mi&1)*32 + quad*8 + 2r + (mi>>1): two ushort2 per (ni,r)
    int rgb0 = m0 + wm * 64;
    int s = rgb0 >> 12, b = (rgb0 >> 11) & 1, n = rgb0 & 2047;
    int kvg0 = s * 2048 + n;               // 64-aligned
#pragma unroll
    for (int ni = 0; ni < 4; ni++) {
      int cg = n0 + wn * 64 + ni * 16 + col;
      int h = cg >> 6, d = cg & 63;
      unsigned short* rowp = &((unsigned short*)Cout_)[((b * 16 + h) * 64 + d) * 8192 + kvg0];
      float bvn = bv[ni];
#pragma unroll
      for (int r = 0; r < 4; r++) {
        ushort2 e, o2;
        e.x = f2bf(acc[0][ni][r] + bvn);   // mi=0 -> kv' = quad*8 + 2r
        e.y = f2bf(acc[2][ni][r] + bvn);   // mi=2 -> kv' = quad*8 + 2r + 1
        o2.x = f2bf(acc[1][ni][r] + bvn);  // mi=1 -> kv' = 32 + quad*8 + 2r
        o2.y = f2bf(acc[3][ni][r] + bvn);  // mi=3 -> kv' = 32 + quad*8 + 2r + 1
        *(ushort2*)&rowp[2 * (quad * 4 + r)] = e;
        *(ushort2*)&rowp[32 + 2 * (quad * 4 + r)] = o2;
      }
    }
  } else {
#pragma unroll
    for (int mi = 0; mi < 4; mi++)
#pragma unroll
      for (int ni = 0; ni < 4; ni++) {
        float vals[4];
#pragma unroll
        for (int r = 0; r < 4; r++) vals[r] = acc[mi][ni][r] + bv[ni];
        if constexpr (MODE == 4) {
          if (isq) {
#pragma unroll
            for (int r = 0; r < 4; r++) vals[r] *= 0.1803368801111601f;  // log2e/8
          }
        }
        int rgb = m0 + wm * 64 + mi * 16 + quad * 4;          // base row (+r)
        int cg  = n0 + wn * 64 + ni * 16 + col;               // col
        if constexpr (MODE == 4) {
          unsigned short* C = (unsigned short*)Cout_;
#pragma unroll
          for (int r = 0; r < 4; r++) C[(rgb + r) * ldc + cg] = f2bf(vals[r]);
        } else {
          if (fp) {
            float* C = (float*)Cout_;
#pragma unroll
            for (int r = 0; r < 4; r++) C[(rgb + r) * ldc + cg] = vals[r];
          } else {
            unsigned short* C = (unsigned short*)Cout_;
#pragma unroll
            for (int r = 0; r < 4; r++) C[(rgb + r) * ldc + cg] = f2bf(vals[r]);
          }
        }
      }
  }
}

// ----------------------------- flash attention -----------------------------
// Grid: 1-D 512 blocks (8 qtiles x 32 bh x 2 halves), 512 threads (8 waves),
// XCD-pinned decode. LDS: K dbuf (16K) + V tribuf (24K) = 40 KiB, 2 blocks/CU.
// T15 deferred-PV pipeline, one barrier per kv-tile:
//   iter t: QK(t) [MFMA] -> { PV(t-1) [MFMA, independent] || exp(t)+pack(t)
//   [VALU] } -> stage(t+1) -> barrier.
// V(t-1) lives in the third V buffer while tile t+1 is staged. aP carried in
// registers across the barrier. Swapped QK^T: lane owns P[q=col][16 kv], packs
// in-register to PV A-fragments (sigma kv' layout matches vt permutation).
// Staging lane-map (512 thr: r0=tid>>3, c0=tid&7): every 8-lane issue group
// covers a full 8-slot XOR permutation = 32 banks (R9 lesson).
// Writes UNNORMALIZED fp32 O-partials + l to workspace; merge kernel combines.
__launch_bounds__(512, 4)
__global__ void attn_kernel(const unsigned short* __restrict__ qbuf,   // [4096,1024]
                            const unsigned short* __restrict__ kbuf,   // [16384,1024]
                            const unsigned short* __restrict__ vt,     // [32*64, 8192] kv-permuted
                            float* __restrict__ po,                    // [2][4096][1024] fp32
                            float* __restrict__ lbuf) {                // [2][2][16][2048]
  __shared__ unsigned short Ks[2][64 * 64];    // double-buffered, swizzled [kv][d]
  __shared__ unsigned short Vs[3][64 * 64];    // TRIPLE-buffered, swizzled [d][kv']
  int tid = threadIdx.x;
  int w = tid >> 6, lane = tid & 63, col = lane & 15, quad = lane >> 4;
  // XCD-pinned decode: xcd = id%8; slot = id/8; qt = slot%8; group = (slot/8)*8+xcd
  int id = blockIdx.x;
  int xcd = id & 7, slot = id >> 3;
  int qt = slot & 7, gsub = slot >> 3;
  int g = gsub * 8 + xcd;                      // 0..63 (bh,half) group
  int bh = g >> 1, half = g & 1;
  int b = bh >> 4, h = bh & 15;
  int q0 = qt * 256;

  // Q fragments direct from global (B-operand: lane holds
  // Q[q = mj*16+col][d = kk*32 + quad*8 .. +7], one contiguous 16B read)
  bf16x8 aQ[2][2];
#pragma unroll
  for (int mj = 0; mj < 2; mj++)
#pragma unroll
    for (int kk = 0; kk < 2; kk++)
      aQ[mj][kk] = ldfrag16(&qbuf[(b * 2048 + q0 + w * 32 + mj * 16 + col) * 1024 +
                                  h * 64 + kk * 32 + quad * 8]);

  // K/V staging: 512 threads cover one 64x64 tile, one uint4 each
  int r0 = tid >> 3, c0 = tid & 7;             // r0 in [0,64), c0 in [0,8)
  const unsigned short* kp = &kbuf[((half * 2) * 4096 + b * 2048 + r0) * 1024 + h * 64 + c0 * 8];
  const unsigned short* vp = &vt[(bh * 64 + r0) * 8192 + half * 4096 + c0 * 8];
  int sdst = r0 * 64 + 8 * (c0 ^ (r0 & 7));    // swizzled LDS slot (shorts)

  const bf16x8 vone = ones8();
  v4f o[2][4];
  v4f acc_l[2] = {v4f{0.f, 0.f, 0.f, 0.f}, v4f{0.f, 0.f, 0.f, 0.f}};
#pragma unroll
  for (int mj = 0; mj < 2; mj++)
#pragma unroll
    for (int di = 0; di < 4; di++) o[mj][di] = v4f{0.f, 0.f, 0.f, 0.f};

  // ---- prologue: stage tile 0; prefetch tile 1; QK(0)+exp+pack; stage tile 1
  {
    uint4 k0 = *(const uint4*)kp, v0 = *(const uint4*)vp;
    *(uint4*)&Ks[0][sdst] = k0;
    *(uint4*)&Vs[0][sdst] = v0;
  }
  kp += 64 * 1024; vp += 64;                   // tile 1 (no shard crossing at t=1)
  uint4 pk = *(const uint4*)kp, pv = *(const uint4*)vp;
  __syncthreads();

  bf16x8 aP[2][2];
  {
    v4f sc[4][2];
#pragma unroll
    for (int ni = 0; ni < 4; ni++)
#pragma unroll
      for (int mj = 0; mj < 2; mj++) sc[ni][mj] = v4f{0.f, 0.f, 0.f, 0.f};
#pragma unroll
    for (int kk = 0; kk < 2; kk++) {
      bf16x8 aK[4];
#pragma unroll
      for (int ni = 0; ni < 4; ni++) {
        int row = ni * 16 + col;
        aK[ni] = ldfrag16(&Ks[0][row * 64 + 8 * ((kk * 4 + quad) ^ (col & 7))]);
      }
#pragma unroll
      for (int ni = 0; ni < 4; ni++)
#pragma unroll
        for (int mj = 0; mj < 2; mj++)
          sc[ni][mj] = __builtin_amdgcn_mfma_f32_16x16x32_bf16(aK[ni], aQ[mj][kk], sc[ni][mj], 0, 0, 0);
    }
#pragma unroll
    for (int ni = 0; ni < 4; ni++)
#pragma unroll
      for (int mj = 0; mj < 2; mj++)
#pragma unroll
        for (int r = 0; r < 4; r++) sc[ni][mj][r] = EXP2F(sc[ni][mj][r]);
#pragma unroll
    for (int mj = 0; mj < 2; mj++)
#pragma unroll
      for (int kk = 0; kk < 2; kk++) {
        union { unsigned int d[4]; bf16x8 v; } u;
#pragma unroll
        for (int t = 0; t < 4; t++)
          u.d[t] = pack2t(sc[kk][mj][t], sc[kk + 2][mj][t]);
        aP[mj][kk] = u.v;
      }
  }
  // stage tile 1 (pk/pv arrived during QK(0) compute)
  *(uint4*)&Ks[1][sdst] = pk;
  *(uint4*)&Vs[1][sdst] = pv;
  __syncthreads();

  const unsigned short* vprev = Vs[0];
  const unsigned short* vcur  = Vs[1];
  const unsigned short* vnext = Vs[2];

  // ---- main loop: t = 1..63; PV(t-1) deferred into iter t
  for (int t = 1; t < 64; t++) {
    const unsigned short* kcur = Ks[t & 1];
    unsigned short* knxt = (unsigned short*)Ks[(t + 1) & 1];
    if (t < 63) {   // prefetch tile t+1 (uniform branch)
      int kstep = (((t + 1) & 31) == 0) ? (2048 + 64) * 1024 : 64 * 1024;
      kp += kstep; vp += 64;
      pk = *(const uint4*)kp; pv = *(const uint4*)vp;
    }

    // QK(t): 16 MFMA -> sc
    v4f sc[4][2];
#pragma unroll
    for (int ni = 0; ni < 4; ni++)
#pragma unroll
      for (int mj = 0; mj < 2; mj++) sc[ni][mj] = v4f{0.f, 0.f, 0.f, 0.f};
#pragma unroll
    for (int kk = 0; kk < 2; kk++) {
      bf16x8 aK[4];
#pragma unroll
      for (int ni = 0; ni < 4; ni++) {
        int row = ni * 16 + col;
        aK[ni] = ldfrag16(&kcur[row * 64 + 8 * ((kk * 4 + quad) ^ (col & 7))]);
      }
#pragma unroll
      for (int ni = 0; ni < 4; ni++)
#pragma unroll
        for (int mj = 0; mj < 2; mj++)
          sc[ni][mj] = __builtin_amdgcn_mfma_f32_16x16x32_bf16(aK[ni], aQ[mj][kk], sc[ni][mj], 0, 0, 0);
    }

    // PV(t-1): 20 MFMA on (aP, vprev) — independent of sc/exp below;
    // compiler interleaves these MFMAs with the exp/pack VALU cluster.
#pragma unroll
    for (int kk = 0; kk < 2; kk++) {
#pragma unroll
      for (int mj = 0; mj < 2; mj++)
        acc_l[mj] = __builtin_amdgcn_mfma_f32_16x16x32_bf16(aP[mj][kk], vone, acc_l[mj], 0, 0, 0);
      bf16x8 bV[4];
#pragma unroll
      for (int di = 0; di < 4; di++) {
        int row = di * 16 + col;
        bV[di] = ldfrag16(&vprev[row * 64 + 8 * ((kk * 4 + quad) ^ (col & 7))]);
      }
#pragma unroll
      for (int mj = 0; mj < 2; mj++)
#pragma unroll
        for (int di = 0; di < 4; di++)
          o[mj][di] = __builtin_amdgcn_mfma_f32_16x16x32_bf16(aP[mj][kk], bV[di], o[mj][di], 0, 0, 0);
    }

    // exp(t) + pack(t) -> new aP (VALU; overlaps PV(t-1) MFMAs above)
#pragma unroll
    for (int ni = 0; ni < 4; ni++)
#pragma unroll
      for (int mj = 0; mj < 2; mj++)
#pragma unroll
        for (int r = 0; r < 4; r++) sc[ni][mj][r] = EXP2F(sc[ni][mj][r]);
    bf16x8 aPn[2][2];
#pragma unroll
    for (int mj = 0; mj < 2; mj++)
#pragma unroll
      for (int kk = 0; kk < 2; kk++) {
        union { unsigned int d[4]; bf16x8 v; } u;
#pragma unroll
        for (int tt = 0; tt < 4; tt++)
          u.d[tt] = pack2t(sc[kk][mj][tt], sc[kk + 2][mj][tt]);
        aPn[mj][kk] = u.v;
      }

    // stage tile t+1 (K -> alt K buf; V -> vnext, distinct from vprev/vcur)
    if (t < 63) {
      *(uint4*)&knxt[sdst] = pk;
      *(uint4*)&((unsigned short*)vnext)[sdst] = pv;
    }

    __syncthreads();   // tile t+1 visible; everyone done with Ks[t&1], vprev

    // carry aP; rotate V buffers
#pragma unroll
    for (int mj = 0; mj < 2; mj++)
#pragma unroll
      for (int kk = 0; kk < 2; kk++) aP[mj][kk] = aPn[mj][kk];
    const unsigned short* vt_ = vprev;
    vprev = vcur; vcur = vnext; vnext = vt_;
  }

  // ---- epilogue: PV(63) (vprev now holds V(63))
#pragma unroll
  for (int kk = 0; kk < 2; kk++) {
#pragma unroll
    for (int mj = 0; mj < 2; mj++)
      acc_l[mj] = __builtin_amdgcn_mfma_f32_16x16x32_bf16(aP[mj][kk], vone, acc_l[mj], 0, 0, 0);
    bf16x8 bV[4];
#pragma unroll
    for (int di = 0; di < 4; di++) {
      int row = di * 16 + col;
      bV[di] = ldfrag16(&vprev[row * 64 + 8 * ((kk * 4 + quad) ^ (col & 7))]);
    }
#pragma unroll
    for (int mj = 0; mj < 2; mj++)
#pragma unroll
      for (int di = 0; di < 4; di++)
        o[mj][di] = __builtin_amdgcn_mfma_f32_16x16x32_bf16(aP[mj][kk], bV[di], o[mj][di], 0, 0, 0);
  }

  // write unnormalized fp32 partials + row sums (merge kernel normalizes)
  float* pb = po + half * 4194304;
#pragma unroll
  for (int mj = 0; mj < 2; mj++)
#pragma unroll
    for (int r = 0; r < 4; r++) {
      int n = q0 + w * 32 + mj * 16 + quad * 4 + r;
      if (col == 0) lbuf[half * 65536 + (b * 16 + h) * 2048 + n] = acc_l[mj][r];
#pragma unroll
      for (int di = 0; di < 4; di++) {
        int c = h * 64 + di * 16 + col;
        pb[(b * 2048 + n) * 1024 + c] = o[mj][di][r];
      }
    }
}

// ------------- merge kv-halves: attn = (O0+O1)/(l0+l1), bf16 -------------
__global__ void merge_halves(const float* __restrict__ po, const float* __restrict__ lbuf,
                             unsigned short* __restrict__ attn) {
  int i = blockIdx.x * 256 + threadIdx.x;      // float4 slot over [4096][256]
  int r = i >> 8, c4 = i & 255;
  float l = lbuf[((r >> 11) * 16 + (c4 >> 4)) * 2048 + (r & 2047)] +
            lbuf[65536 + ((r >> 11) * 16 + (c4 >> 4)) * 2048 + (r & 2047)];
  float inv = 1.f / l;
  float4 a = ((const float4*)po)[i];
  float4 b = ((const float4*)po)[1048576 + i];
  ushort4 o;
  o.x = f2bf((a.x + b.x) * inv); o.y = f2bf((a.y + b.y) * inv);
  o.z = f2bf((a.z + b.z) * inv); o.w = f2bf((a.w + b.w) * inv);
  ((ushort4*)attn)[i] = o;
}

extern "C" void kernel_launch(void* const* d_in, const int* in_sizes, int n_in,
                              void* d_out, int out_size, void* d_ws, size_t ws_size,
                              hipStream_t stream) {
  const void* x      = d_in[0];  // [4,2,2048,1024]
  const void* w_qkv  = d_in[1];  // [1024,3072]
  const void* b_qkv  = d_in[2];  // [3072]
  const void* w_proj = d_in[3];  // [1024,1024]
  const void* b_proj = d_in[4];  // [1024]

  char* ws = (char*)d_ws;
  unsigned short* xb   = (unsigned short*)(ws);                // 33,554,432 B
  unsigned short* kk   = (unsigned short*)(ws + 33554432);     // 33,554,432 B
  unsigned short* vt   = (unsigned short*)(ws + 67108864);     // 33,554,432 B
  unsigned short* q0b  = (unsigned short*)(ws + 100663296);    //  8,388,608 B
  unsigned short* attn = (unsigned short*)(ws + 109051904);    //  8,388,608 B
  unsigned short* wt1  = (unsigned short*)(ws + 117440512);    //  6,291,456 B
  unsigned short* wt2  = (unsigned short*)(ws + 123731968);    //  2,097,152 B
  unsigned short* bq   = (unsigned short*)(ws + 125829120);    //      6,144 B
  unsigned short* bp   = (unsigned short*)(ws + 125835264);    //      2,048 B
  int* flag            = (int*)(ws + 125837312);               //          4 B
  // aliased regions (dead by the time they're reused):
  float* po   = (float*)xb;        // 2 x 16.78 MB fp32 O-partials (xb dead after GEMMs)
  float* lbuf = (float*)wt1;       // 2 x 256 KB row sums (wt1 dead after GEMMs)

  detect_dtype<<<1, 64, 0, stream>>>((const unsigned short*)x, flag);

  conv_to_bf16<<<16384, 256, 0, stream>>>(x, xb, 4194304, flag);
  conv_bias<<<4, 256, 0, stream>>>(b_qkv, b_proj, bq, bp, flag);
  trans_both<<<dim3(128, 32), dim3(32, 8), 0, stream>>>(w_qkv, w_proj, wt1, wt2, flag);

  // ONE fused k+q+v projection launch: 2304 blocks = 3.0 rounds at 3/CU,
  // XCD-pinned so A-panel sharers are consecutive on one XCD.
  gemm_bt<4><<<2304, 256, 0, stream>>>(xb, wt1 + 1024 * 1024, bq + 1024, kk,
                                       1024, 1024, flag,
                                       wt1, bq, q0b,
                                       wt1 + 2048 * 1024, bq + 2048, vt);

  // flash attention: 512 blocks x 512 threads (2 blocks/CU), XCD-pinned,
  // deferred-PV pipeline
  attn_kernel<<<512, 512, 0, stream>>>(q0b, kk, vt, po, lbuf);
  merge_halves<<<4096, 256, 0, stream>>>(po, lbuf, attn);

  // output projection (dtype-flag epilogue), XCD-pinned 1-D grid
  gemm_bt<2><<<256, 256, 0, stream>>>(attn, wt2, bp, d_out,
                                      1024, 1024, flag,
                                      nullptr, nullptr, nullptr,
                                      nullptr, nullptr, nullptr);
}

// Round 13
// 265.398 us; speedup vs baseline: 1.1234x; 1.0818x over previous
//
#include <hip/hip_runtime.h>
#include <hip/hip_bf16.h>

// RingAttention on MI355X (gfx950). Ring online-softmax merge over S=4 KV
// shards == one flash pass over S*N=8192 keys with rank-0 queries.
// S=4, B=2, N=2048, C=1024, H=16, D=64.
// No-max softmax (scores bounded): p = exp2(s'), log2e/8 folded into q proj.
// R13 changes (GEMM; R12 ledger: GEMMs ~110us at ~700 TF, 2-barrier drain
// stall is the documented ~20% overhead of this structure):
//  - BK 32 -> 64: halves barrier count (16 iters at K=1024), doubles MFMA per
//    drain (32). LDS 16->32KB, still 3 blocks/CU (96KB).
//  - stride 64-shorts rows would 16-way conflict on ds_read_b128 -> XOR
//    swizzle, gld_lds-compatible form (rule #21/m173): LDS linear, GLOBAL
//    source chunk pre-swizzled (c ^ (row&7), same 128B row -> coalesced),
//    fragment reads XOR chunk ((kk*4+quad) ^ (col&7)) — attn's proven pattern.
// Frozen: attn (R10/R12: 135us, T15 deferred-PV, v_perm pack, XOR swizzle,
// XCD pin), fused-qkv decode (2304 blk = 3.0 rounds), merge, out-proj decode.

typedef __bf16 bf16x8 __attribute__((ext_vector_type(8)));
typedef float v4f __attribute__((ext_vector_type(4)));

#if __has_builtin(__builtin_amdgcn_exp2f)
#define EXP2F(x) __builtin_amdgcn_exp2f(x)
#else
#define EXP2F(x) exp2f(x)
#endif

__device__ __forceinline__ float bf2f(unsigned short h) {
  union { unsigned int u; float f; } a; a.u = ((unsigned int)h) << 16; return a.f;
}
__device__ __forceinline__ unsigned short f2bf(float f) {
  union { float f; unsigned int u; } a; a.f = f;
  unsigned int u = a.u;
  unsigned int r = (u + 0x7fffu + ((u >> 16) & 1u)) >> 16;  // RNE
  return (unsigned short)r;
}
// truncating pack of two fp32 -> bf16x2 (denominator uses the same bits via
// MFMA). v_perm_b32: D = [b.b3, b.b2, a.b3, a.b2] -> selector 0x07060302.
__device__ __forceinline__ unsigned int pack2t(float a, float b) {
  union { float f; unsigned int u; } ua, ub; ua.f = a; ub.f = b;
#if __has_builtin(__builtin_amdgcn_perm)
  return __builtin_amdgcn_perm(ub.u, ua.u, 0x07060302u);
#else
  return (ua.u >> 16) | (ub.u & 0xffff0000u);
#endif
}
// 16B-aligned fragment load (LDS or global)
__device__ __forceinline__ bf16x8 ldfrag16(const unsigned short* p) {
  union { uint4 u; bf16x8 v; } x; x.u = *(const uint4*)p; return x.v;
}
__device__ __forceinline__ bf16x8 ones8() {
  union { unsigned short s[8]; bf16x8 v; } x;
#pragma unroll
  for (int i = 0; i < 8; i++) x.s[i] = 0x3F80;  // 1.0 bf16
  return x.v;
}
// async global->LDS, 16B per lane; LDS dest = wave-uniform base + lane*16
__device__ __forceinline__ void gld_lds16(const unsigned short* g, unsigned short* l) {
  __builtin_amdgcn_global_load_lds((__attribute__((address_space(1))) void*)g,
                                   (__attribute__((address_space(3))) void*)l, 16, 0, 0);
}

// ---------------- runtime dtype detection ----------------
__global__ void detect_dtype(const unsigned short* __restrict__ x, int* flag) {
  __shared__ int cnt;
  if (threadIdx.x == 0) cnt = 0;
  __syncthreads();
  int sane = 0;
#pragma unroll
  for (int j = 0; j < 4; j++) {
    unsigned short v = x[2 * (threadIdx.x + 64 * j)];
    int e = (v >> 7) & 0xFF;
    if (e >= 90 && e <= 140) sane++;
  }
  atomicAdd(&cnt, sane);
  __syncthreads();
  if (threadIdx.x == 0) *flag = (cnt > 160) ? 0 : 1;  // 1 => fp32 inputs
}

// ---------------- dtype-flag conversion to bf16 (4 elems/thread) ----------------
__global__ void conv_to_bf16(const void* __restrict__ in, unsigned short* __restrict__ out,
                             int n4, const int* __restrict__ flag) {
  int i = blockIdx.x * blockDim.x + threadIdx.x;
  if (i >= n4) return;
  if (*flag) {
    float4 v = ((const float4*)in)[i];
    ushort4 o;
    o.x = f2bf(v.x); o.y = f2bf(v.y); o.z = f2bf(v.z); o.w = f2bf(v.w);
    ((ushort4*)out)[i] = o;
  } else {
    ((ushort4*)out)[i] = ((const ushort4*)in)[i];
  }
}

// ---------------- both biases in one launch (grid 4 x 256) ----------------
__global__ void conv_bias(const void* __restrict__ bq_in, const void* __restrict__ bp_in,
                          unsigned short* __restrict__ bq, unsigned short* __restrict__ bp,
                          const int* __restrict__ flag) {
  int i = blockIdx.x * 256 + threadIdx.x;      // 0..1023 ushort4 slots
  const void* in = (i < 768) ? bq_in : bp_in;
  unsigned short* out = (i < 768) ? bq : bp;
  int j = (i < 768) ? i : i - 768;
  if (*flag) {
    float4 v = ((const float4*)in)[j];
    ushort4 o;
    o.x = f2bf(v.x); o.y = f2bf(v.y); o.z = f2bf(v.z); o.w = f2bf(v.w);
    ((ushort4*)out)[j] = o;
  } else {
    ((ushort4*)out)[j] = ((const ushort4*)in)[j];
  }
}

// ------------- both weight transposes in one launch : out[C][R] = in[R][C] -------------
__global__ void trans_both(const void* __restrict__ wqkv, const void* __restrict__ wproj,
                           unsigned short* __restrict__ wt1, unsigned short* __restrict__ wt2,
                           const int* __restrict__ flag) {
  __shared__ unsigned short t[32][33];
  int tx = threadIdx.x, ty = threadIdx.y;
  int bx = blockIdx.x;
  const void* in; unsigned short* out; int C, c0;
  if (bx < 96) { in = wqkv; out = wt1; C = 3072; c0 = bx * 32; }
  else         { in = wproj; out = wt2; C = 1024; c0 = (bx - 96) * 32; }
  const int R = 1024;
  int r0 = blockIdx.y * 32;
  int fp = *flag;
#pragma unroll
  for (int j = 0; j < 32; j += 8) {
    unsigned short v;
    if (fp) v = f2bf(((const float*)in)[(r0 + ty + j) * C + c0 + tx]);
    else    v = ((const unsigned short*)in)[(r0 + ty + j) * C + c0 + tx];
    t[ty + j][tx] = v;
  }
  __syncthreads();
#pragma unroll
  for (int j = 0; j < 32; j += 8) out[(c0 + ty + j) * R + r0 + tx] = t[tx][ty + j];
}

// --------------------- tiled bf16 GEMM: C = A @ Bt^T + bias ---------------------
// 128x128 tile, BK=64 (16 iters at K=1024), LDS 128x64 per matrix (32KB total,
// 3 blocks/CU). Staging via global_load_lds w=16, lane-linear LDS; the global
// source 16B-chunk index is pre-swizzled (c ^ (row&7)) so the swizzled
// fragment reads ((kk*4+quad) ^ (col&7)) are bank-conflict-free at the 128B
// row stride (T2 / rule #21 / m173 — same pattern as attn staging).
// MODE 4: fused qkv projection, 1-D grid 2304, XCD-pinned decode:
//   xcd = id&7; t = id>>3 (288/XCD); x = t&7 (fastest); yl = t>>3 (36/XCD);
//   y = xcd*36 + yl in [0,288): y<256 -> pair j=y>>1 (even=k, odd=v, same A
//   rows m0=j*128); y>=256 -> q (m0=(y-256)*128, scaled by log2e/8).
//   v uses the sigma kv' epilogue into vt; k/q write plain bf16.
// MODE 2: final output proj (fp32/bf16 per *flag), 1-D grid 256, same swizzle.
template <int MODE>
__launch_bounds__(256, 3)
__global__ void gemm_bt(const unsigned short* __restrict__ A,
                        const unsigned short* __restrict__ Bt,
                        const unsigned short* __restrict__ bias,
                        void* __restrict__ Cout,
                        int K, int ldc, const int* __restrict__ flag,
                        const unsigned short* Bt2, const unsigned short* bias2,
                        void* Cout2,
                        const unsigned short* Bt3, const unsigned short* bias3,
                        void* Cout3) {
  __shared__ unsigned short As[128 * 64];
  __shared__ unsigned short Bs[128 * 64];
  int tid = threadIdx.x;
  int w = tid >> 6, lane = tid & 63, col = lane & 15, quad = lane >> 4;
  int wm = w >> 1, wn = w & 1;
  const unsigned short* Bt_ = Bt;
  const unsigned short* bias_ = bias;
  void* Cout_ = Cout;
  bool isq = false, isv = false;
  int n0, m0;
  if constexpr (MODE == 4) {
    int id = blockIdx.x;                  // 2304 blocks
    int xcd = id & 7, t = id >> 3;        // t in [0,288)
    n0 = (t & 7) * 128;                   // x fastest within XCD
    int y = xcd * 36 + (t >> 3);          // y in [0,288)
    if (y < 256) {
      m0 = (y >> 1) * 128;                // k/v pair shares A rows
      if (y & 1) { isv = true; Bt_ = Bt3; bias_ = bias3; Cout_ = Cout3; }
    } else {
      m0 = (y - 256) * 128;               // q (shard-0 rows)
      isq = true; Bt_ = Bt2; bias_ = bias2; Cout_ = Cout2;
    }
  } else {  // MODE 2: 256 blocks, 32 m-tiles, 4 per XCD
    int id = blockIdx.x;
    int xcd = id & 7, t = id >> 3;        // t in [0,32)
    n0 = (t & 7) * 128;
    m0 = (xcd * 4 + (t >> 3)) * 128;
  }
  int fp = 0;
  if constexpr (MODE == 2) fp = *flag;

  v4f acc[4][4];
#pragma unroll
  for (int i = 0; i < 4; i++)
#pragma unroll
    for (int j = 0; j < 4; j++) acc[i][j] = v4f{0.f, 0.f, 0.f, 0.f};

  // staging (BK=64): slot s = row*8 + c (row in [0,128), c in [0,8), 16B each).
  // Thread covers s = tid (rows 0..31) and s = tid+256 (rows 32..63); two more
  // rows blocks via the 64-row halves: rows 0..31 and 32..63 of each 64-half?
  // Layout: s in [0,512) covers rows 0..63; s in [512,1024) rows 64..127.
  // Thread t covers s = t and s = t + 256 and ... 1024 slots / 256 thr = 4.
  // Per matrix: 4 slots/thread -> (tid), (tid+256), (tid+512), (tid+768).
  int row0 = tid >> 3, c0 = tid & 7;           // row0 in [0,32), c0 in [0,8)
  int sw = c0;                                 // chunk idx; global pre-swizzled
  // rows row0, row0+32, row0+64, row0+96 share (row&7) = row0&7
  int cg0 = (sw ^ (row0 & 7)) * 8;             // pre-swizzled global chunk offset
  const unsigned short* ga0 = &A[(m0 + row0) * K + cg0];
  const unsigned short* ga1 = ga0 + 32 * K;
  const unsigned short* ga2 = ga0 + 64 * K;
  const unsigned short* ga3 = ga0 + 96 * K;
  const unsigned short* gb0 = &Bt_[(n0 + row0) * K + cg0];
  const unsigned short* gb1 = gb0 + 32 * K;
  const unsigned short* gb2 = gb0 + 64 * K;
  const unsigned short* gb3 = gb0 + 96 * K;
  // wave-uniform LDS bases: wave w's lanes cover slots 64w..64w+63 (linear)
  unsigned short* lA0 = &As[w * 512];          // slots  64w.. -> rows 8w..8w+7
  unsigned short* lA1 = &As[2048 + w * 512];   // +256 slots -> rows 32+8w..
  unsigned short* lA2 = &As[4096 + w * 512];
  unsigned short* lA3 = &As[6144 + w * 512];
  unsigned short* lB0 = &Bs[w * 512];
  unsigned short* lB1 = &Bs[2048 + w * 512];
  unsigned short* lB2 = &Bs[4096 + w * 512];
  unsigned short* lB3 = &Bs[6144 + w * 512];

  int niter = K >> 6;
  for (int it = 0; it < niter; it++) {
    __syncthreads();                     // prev compute done; LDS writable
    gld_lds16(ga0, lA0); gld_lds16(ga1, lA1);
    gld_lds16(ga2, lA2); gld_lds16(ga3, lA3);
    gld_lds16(gb0, lB0); gld_lds16(gb1, lB1);
    gld_lds16(gb2, lB2); gld_lds16(gb3, lB3);
    ga0 += 64; ga1 += 64; ga2 += 64; ga3 += 64;
    gb0 += 64; gb1 += 64; gb2 += 64; gb3 += 64;
    __syncthreads();                     // vmcnt drained by compiler -> tile ready
#pragma unroll
    for (int kk = 0; kk < 2; kk++) {
      bf16x8 af[4], bfr[4];
#pragma unroll
      for (int mi = 0; mi < 4; mi++) {
        int row = wm * 64 + mi * 16 + col;
        af[mi] = ldfrag16(&As[row * 64 + 8 * ((kk * 4 + quad) ^ (col & 7))]);
      }
#pragma unroll
      for (int ni = 0; ni < 4; ni++) {
        int row = wn * 64 + ni * 16 + col;
        bfr[ni] = ldfrag16(&Bs[row * 64 + 8 * ((kk * 4 + quad) ^ (col & 7))]);
      }
#pragma unroll
      for (int mi = 0; mi < 4; mi++)
#pragma unroll
        for (int ni = 0; ni < 4; ni++)
          acc[mi][ni] = __builtin_amdgcn_mfma_f32_16x16x32_bf16(af[mi], bfr[ni], acc[mi][ni], 0, 0, 0);
    }
  }

  float bv[4];
#pragma unroll
  for (int ni = 0; ni < 4; ni++) bv[ni] = bf2f(bias_[n0 + wn * 64 + ni * 16 + col]);

  if (MODE == 4 && isv) {
    // packed V store: rows m0+wm*64..+63 form one 64-kv block;
    // kv' = (mi&1)*32 + quad*8 + 2r + (mi>>1): two ushort2 per (ni,r)
    int rgb0 = m0 + wm * 64;
    int s = rgb0 >> 12, b = (rgb0 >> 11) & 1, n = rgb0 & 2047;
    int kvg0 = s * 2048 + n;               // 64-aligned
#pragma unroll
    for (int ni = 0; ni < 4; ni++) {
      int cg = n0 + wn * 64 + ni * 16 + col;
      int h = cg >> 6, d = cg & 63;
      unsigned short* rowp = &((unsigned short*)Cout_)[((b * 16 + h) * 64 + d) * 8192 + kvg0];
      float bvn = bv[ni];
#pragma unroll
      for (int r = 0; r < 4; r++) {
        ushort2 e, o2;
        e.x = f2bf(acc[0][ni][r] + bvn);   // mi=0 -> kv' = quad*8 + 2r
        e.y = f2bf(acc[2][ni][r] + bvn);   // mi=2 -> kv' = quad*8 + 2r + 1
        o2.x = f2bf(acc[1][ni][r] + bvn);  // mi=1 -> kv' = 32 + quad*8 + 2r
        o2.y = f2bf(acc[3][ni][r] + bvn);  // mi=3 -> kv' = 32 + quad*8 + 2r + 1
        *(ushort2*)&rowp[2 * (quad * 4 + r)] = e;
        *(ushort2*)&rowp[32 + 2 * (quad * 4 + r)] = o2;
      }
    }
  } else {
#pragma unroll
    for (int mi = 0; mi < 4; mi++)
#pragma unroll
      for (int ni = 0; ni < 4; ni++) {
        float vals[4];
#pragma unroll
        for (int r = 0; r < 4; r++) vals[r] = acc[mi][ni][r] + bv[ni];
        if constexpr (MODE == 4) {
          if (isq) {
#pragma unroll
            for (int r = 0; r < 4; r++) vals[r] *= 0.1803368801111601f;  // log2e/8
          }
        }
        int rgb = m0 + wm * 64 + mi * 16 + quad * 4;          // base row (+r)
        int cg  = n0 + wn * 64 + ni * 16 + col;               // col
        if constexpr (MODE == 4) {
          unsigned short* C = (unsigned short*)Cout_;
#pragma unroll
          for (int r = 0; r < 4; r++) C[(rgb + r) * ldc + cg] = f2bf(vals[r]);
        } else {
          if (fp) {
            float* C = (float*)Cout_;
#pragma unroll
            for (int r = 0; r < 4; r++) C[(rgb + r) * ldc + cg] = vals[r];
          } else {
            unsigned short* C = (unsigned short*)Cout_;
#pragma unroll
            for (int r = 0; r < 4; r++) C[(rgb + r) * ldc + cg] = f2bf(vals[r]);
          }
        }
      }
  }
}

// ----------------------------- flash attention -----------------------------
// Grid: 1-D 512 blocks (8 qtiles x 32 bh x 2 halves), 512 threads (8 waves),
// XCD-pinned decode. LDS: K dbuf (16K) + V tribuf (24K) = 40 KiB, 2 blocks/CU.
// T15 deferred-PV pipeline, one barrier per kv-tile:
//   iter t: QK(t) [MFMA] -> { PV(t-1) [MFMA, independent] || exp(t)+pack(t)
//   [VALU] } -> stage(t+1) -> barrier.
// V(t-1) lives in the third V buffer while tile t+1 is staged. aP carried in
// registers across the barrier. Swapped QK^T: lane owns P[q=col][16 kv], packs
// in-register to PV A-fragments (sigma kv' layout matches vt permutation).
// Staging lane-map (512 thr: r0=tid>>3, c0=tid&7): every 8-lane issue group
// covers a full 8-slot XOR permutation = 32 banks (R9 lesson).
// Writes UNNORMALIZED fp32 O-partials + l to workspace; merge kernel combines.
__launch_bounds__(512, 4)
__global__ void attn_kernel(const unsigned short* __restrict__ qbuf,   // [4096,1024]
                            const unsigned short* __restrict__ kbuf,   // [16384,1024]
                            const unsigned short* __restrict__ vt,     // [32*64, 8192] kv-permuted
                            float* __restrict__ po,                    // [2][4096][1024] fp32
                            float* __restrict__ lbuf) {                // [2][2][16][2048]
  __shared__ unsigned short Ks[2][64 * 64];    // double-buffered, swizzled [kv][d]
  __shared__ unsigned short Vs[3][64 * 64];    // TRIPLE-buffered, swizzled [d][kv']
  int tid = threadIdx.x;
  int w = tid >> 6, lane = tid & 63, col = lane & 15, quad = lane >> 4;
  // XCD-pinned decode: xcd = id%8; slot = id/8; qt = slot%8; group = (slot/8)*8+xcd
  int id = blockIdx.x;
  int xcd = id & 7, slot = id >> 3;
  int qt = slot & 7, gsub = slot >> 3;
  int g = gsub * 8 + xcd;                      // 0..63 (bh,half) group
  int bh = g >> 1, half = g & 1;
  int b = bh >> 4, h = bh & 15;
  int q0 = qt * 256;

  // Q fragments direct from global (B-operand: lane holds
  // Q[q = mj*16+col][d = kk*32 + quad*8 .. +7], one contiguous 16B read)
  bf16x8 aQ[2][2];
#pragma unroll
  for (int mj = 0; mj < 2; mj++)
#pragma unroll
    for (int kk = 0; kk < 2; kk++)
      aQ[mj][kk] = ldfrag16(&qbuf[(b * 2048 + q0 + w * 32 + mj * 16 + col) * 1024 +
                                  h * 64 + kk * 32 + quad * 8]);

  // K/V staging: 512 threads cover one 64x64 tile, one uint4 each
  int r0 = tid >> 3, c0 = tid & 7;             // r0 in [0,64), c0 in [0,8)
  const unsigned short* kp = &kbuf[((half * 2) * 4096 + b * 2048 + r0) * 1024 + h * 64 + c0 * 8];
  const unsigned short* vp = &vt[(bh * 64 + r0) * 8192 + half * 4096 + c0 * 8];
  int sdst = r0 * 64 + 8 * (c0 ^ (r0 & 7));    // swizzled LDS slot (shorts)

  const bf16x8 vone = ones8();
  v4f o[2][4];
  v4f acc_l[2] = {v4f{0.f, 0.f, 0.f, 0.f}, v4f{0.f, 0.f, 0.f, 0.f}};
#pragma unroll
  for (int mj = 0; mj < 2; mj++)
#pragma unroll
    for (int di = 0; di < 4; di++) o[mj][di] = v4f{0.f, 0.f, 0.f, 0.f};

  // ---- prologue: stage tile 0; prefetch tile 1; QK(0)+exp+pack; stage tile 1
  {
    uint4 k0 = *(const uint4*)kp, v0 = *(const uint4*)vp;
    *(uint4*)&Ks[0][sdst] = k0;
    *(uint4*)&Vs[0][sdst] = v0;
  }
  kp += 64 * 1024; vp += 64;                   // tile 1 (no shard crossing at t=1)
  uint4 pk = *(const uint4*)kp, pv = *(const uint4*)vp;
  __syncthreads();

  bf16x8 aP[2][2];
  {
    v4f sc[4][2];
#pragma unroll
    for (int ni = 0; ni < 4; ni++)
#pragma unroll
      for (int mj = 0; mj < 2; mj++) sc[ni][mj] = v4f{0.f, 0.f, 0.f, 0.f};
#pragma unroll
    for (int kk = 0; kk < 2; kk++) {
      bf16x8 aK[4];
#pragma unroll
      for (int ni = 0; ni < 4; ni++) {
        int row = ni * 16 + col;
        aK[ni] = ldfrag16(&Ks[0][row * 64 + 8 * ((kk * 4 + quad) ^ (col & 7))]);
      }
#pragma unroll
      for (int ni = 0; ni < 4; ni++)
#pragma unroll
        for (int mj = 0; mj < 2; mj++)
          sc[ni][mj] = __builtin_amdgcn_mfma_f32_16x16x32_bf16(aK[ni], aQ[mj][kk], sc[ni][mj], 0, 0, 0);
    }
#pragma unroll
    for (int ni = 0; ni < 4; ni++)
#pragma unroll
      for (int mj = 0; mj < 2; mj++)
#pragma unroll
        for (int r = 0; r < 4; r++) sc[ni][mj][r] = EXP2F(sc[ni][mj][r]);
#pragma unroll
    for (int mj = 0; mj < 2; mj++)
#pragma unroll
      for (int kk = 0; kk < 2; kk++) {
        union { unsigned int d[4]; bf16x8 v; } u;
#pragma unroll
        for (int t = 0; t < 4; t++)
          u.d[t] = pack2t(sc[kk][mj][t], sc[kk + 2][mj][t]);
        aP[mj][kk] = u.v;
      }
  }
  // stage tile 1 (pk/pv arrived during QK(0) compute)
  *(uint4*)&Ks[1][sdst] = pk;
  *(uint4*)&Vs[1][sdst] = pv;
  __syncthreads();

  const unsigned short* vprev = Vs[0];
  const unsigned short* vcur  = Vs[1];
  const unsigned short* vnext = Vs[2];

  // ---- main loop: t = 1..63; PV(t-1) deferred into iter t
  for (int t = 1; t < 64; t++) {
    const unsigned short* kcur = Ks[t & 1];
    unsigned short* knxt = (unsigned short*)Ks[(t + 1) & 1];
    if (t < 63) {   // prefetch tile t+1 (uniform branch)
      int kstep = (((t + 1) & 31) == 0) ? (2048 + 64) * 1024 : 64 * 1024;
      kp += kstep; vp += 64;
      pk = *(const uint4*)kp; pv = *(const uint4*)vp;
    }

    // QK(t): 16 MFMA -> sc
    v4f sc[4][2];
#pragma unroll
    for (int ni = 0; ni < 4; ni++)
#pragma unroll
      for (int mj = 0; mj < 2; mj++) sc[ni][mj] = v4f{0.f, 0.f, 0.f, 0.f};
#pragma unroll
    for (int kk = 0; kk < 2; kk++) {
      bf16x8 aK[4];
#pragma unroll
      for (int ni = 0; ni < 4; ni++) {
        int row = ni * 16 + col;
        aK[ni] = ldfrag16(&kcur[row * 64 + 8 * ((kk * 4 + quad) ^ (col & 7))]);
      }
#pragma unroll
      for (int ni = 0; ni < 4; ni++)
#pragma unroll
        for (int mj = 0; mj < 2; mj++)
          sc[ni][mj] = __builtin_amdgcn_mfma_f32_16x16x32_bf16(aK[ni], aQ[mj][kk], sc[ni][mj], 0, 0, 0);
    }

    // PV(t-1): 20 MFMA on (aP, vprev) — independent of sc/exp below;
    // compiler interleaves these MFMAs with the exp/pack VALU cluster.
#pragma unroll
    for (int kk = 0; kk < 2; kk++) {
#pragma unroll
      for (int mj = 0; mj < 2; mj++)
        acc_l[mj] = __builtin_amdgcn_mfma_f32_16x16x32_bf16(aP[mj][kk], vone, acc_l[mj], 0, 0, 0);
      bf16x8 bV[4];
#pragma unroll
      for (int di = 0; di < 4; di++) {
        int row = di * 16 + col;
        bV[di] = ldfrag16(&vprev[row * 64 + 8 * ((kk * 4 + quad) ^ (col & 7))]);
      }
#pragma unroll
      for (int mj = 0; mj < 2; mj++)
#pragma unroll
        for (int di = 0; di < 4; di++)
          o[mj][di] = __builtin_amdgcn_mfma_f32_16x16x32_bf16(aP[mj][kk], bV[di], o[mj][di], 0, 0, 0);
    }

    // exp(t) + pack(t) -> new aP (VALU; overlaps PV(t-1) MFMAs above)
#pragma unroll
    for (int ni = 0; ni < 4; ni++)
#pragma unroll
      for (int mj = 0; mj < 2; mj++)
#pragma unroll
        for (int r = 0; r < 4; r++) sc[ni][mj][r] = EXP2F(sc[ni][mj][r]);
    bf16x8 aPn[2][2];
#pragma unroll
    for (int mj = 0; mj < 2; mj++)
#pragma unroll
      for (int kk = 0; kk < 2; kk++) {
        union { unsigned int d[4]; bf16x8 v; } u;
#pragma unroll
        for (int tt = 0; tt < 4; tt++)
          u.d[tt] = pack2t(sc[kk][mj][tt], sc[kk + 2][mj][tt]);
        aPn[mj][kk] = u.v;
      }

    // stage tile t+1 (K -> alt K buf; V -> vnext, distinct from vprev/vcur)
    if (t < 63) {
      *(uint4*)&knxt[sdst] = pk;
      *(uint4*)&((unsigned short*)vnext)[sdst] = pv;
    }

    __syncthreads();   // tile t+1 visible; everyone done with Ks[t&1], vprev

    // carry aP; rotate V buffers
#pragma unroll
    for (int mj = 0; mj < 2; mj++)
#pragma unroll
      for (int kk = 0; kk < 2; kk++) aP[mj][kk] = aPn[mj][kk];
    const unsigned short* vt_ = vprev;
    vprev = vcur; vcur = vnext; vnext = vt_;
  }

  // ---- epilogue: PV(63) (vprev now holds V(63))
#pragma unroll
  for (int kk = 0; kk < 2; kk++) {
#pragma unroll
    for (int mj = 0; mj < 2; mj++)
      acc_l[mj] = __builtin_amdgcn_mfma_f32_16x16x32_bf16(aP[mj][kk], vone, acc_l[mj], 0, 0, 0);
    bf16x8 bV[4];
#pragma unroll
    for (int di = 0; di < 4; di++) {
      int row = di * 16 + col;
      bV[di] = ldfrag16(&vprev[row * 64 + 8 * ((kk * 4 + quad) ^ (col & 7))]);
    }
#pragma unroll
    for (int mj = 0; mj < 2; mj++)
#pragma unroll
      for (int di = 0; di < 4; di++)
        o[mj][di] = __builtin_amdgcn_mfma_f32_16x16x32_bf16(aP[mj][kk], bV[di], o[mj][di], 0, 0, 0);
  }

  // write unnormalized fp32 partials + row sums (merge kernel normalizes)
  float* pb = po + half * 4194304;
#pragma unroll
  for (int mj = 0; mj < 2; mj++)
#pragma unroll
    for (int r = 0; r < 4; r++) {
      int n = q0 + w * 32 + mj * 16 + quad * 4 + r;
      if (col == 0) lbuf[half * 65536 + (b * 16 + h) * 2048 + n] = acc_l[mj][r];
#pragma unroll
      for (int di = 0; di < 4; di++) {
        int c = h * 64 + di * 16 + col;
        pb[(b * 2048 + n) * 1024 + c] = o[mj][di][r];
      }
    }
}

// ------------- merge kv-halves: attn = (O0+O1)/(l0+l1), bf16 -------------
__global__ void merge_halves(const float* __restrict__ po, const float* __restrict__ lbuf,
                             unsigned short* __restrict__ attn) {
  int i = blockIdx.x * 256 + threadIdx.x;      // float4 slot over [4096][256]
  int r = i >> 8, c4 = i & 255;
  float l = lbuf[((r >> 11) * 16 + (c4 >> 4)) * 2048 + (r & 2047)] +
            lbuf[65536 + ((r >> 11) * 16 + (c4 >> 4)) * 2048 + (r & 2047)];
  float inv = 1.f / l;
  float4 a = ((const float4*)po)[i];
  float4 b = ((const float4*)po)[1048576 + i];
  ushort4 o;
  o.x = f2bf((a.x + b.x) * inv); o.y = f2bf((a.y + b.y) * inv);
  o.z = f2bf((a.z + b.z) * inv); o.w = f2bf((a.w + b.w) * inv);
  ((ushort4*)attn)[i] = o;
}

extern "C" void kernel_launch(void* const* d_in, const int* in_sizes, int n_in,
                              void* d_out, int out_size, void* d_ws, size_t ws_size,
                              hipStream_t stream) {
  const void* x      = d_in[0];  // [4,2,2048,1024]
  const void* w_qkv  = d_in[1];  // [1024,3072]
  const void* b_qkv  = d_in[2];  // [3072]
  const void* w_proj = d_in[3];  // [1024,1024]
  const void* b_proj = d_in[4];  // [1024]

  char* ws = (char*)d_ws;
  unsigned short* xb   = (unsigned short*)(ws);                // 33,554,432 B
  unsigned short* kk   = (unsigned short*)(ws + 33554432);     // 33,554,432 B
  unsigned short* vt   = (unsigned short*)(ws + 67108864);     // 33,554,432 B
  unsigned short* q0b  = (unsigned short*)(ws + 100663296);    //  8,388,608 B
  unsigned short* attn = (unsigned short*)(ws + 109051904);    //  8,388,608 B
  unsigned short* wt1  = (unsigned short*)(ws + 117440512);    //  6,291,456 B
  unsigned short* wt2  = (unsigned short*)(ws + 123731968);    //  2,097,152 B
  unsigned short* bq   = (unsigned short*)(ws + 125829120);    //      6,144 B
  unsigned short* bp   = (unsigned short*)(ws + 125835264);    //      2,048 B
  int* flag            = (int*)(ws + 125837312);               //          4 B
  // aliased regions (dead by the time they're reused):
  float* po   = (float*)xb;        // 2 x 16.78 MB fp32 O-partials (xb dead after GEMMs)
  float* lbuf = (float*)wt1;       // 2 x 256 KB row sums (wt1 dead after GEMMs)

  detect_dtype<<<1, 64, 0, stream>>>((const unsigned short*)x, flag);

  conv_to_bf16<<<16384, 256, 0, stream>>>(x, xb, 4194304, flag);
  conv_bias<<<4, 256, 0, stream>>>(b_qkv, b_proj, bq, bp, flag);
  trans_both<<<dim3(128, 32), dim3(32, 8), 0, stream>>>(w_qkv, w_proj, wt1, wt2, flag);

  // ONE fused k+q+v projection launch: 2304 blocks = 3.0 rounds at 3/CU,
  // XCD-pinned so A-panel sharers are consecutive on one XCD. BK=64.
  gemm_bt<4><<<2304, 256, 0, stream>>>(xb, wt1 + 1024 * 1024, bq + 1024, kk,
                                       1024, 1024, flag,
                                       wt1, bq, q0b,
                                       wt1 + 2048 * 1024, bq + 2048, vt);

  // flash attention: 512 blocks x 512 threads (2 blocks/CU), XCD-pinned,
  // deferred-PV pipeline
  attn_kernel<<<512, 512, 0, stream>>>(q0b, kk, vt, po, lbuf);
  merge_halves<<<4096, 256, 0, stream>>>(po, lbuf, attn);

  // output projection (dtype-flag epilogue), XCD-pinned 1-D grid, BK=64
  gemm_bt<2><<<256, 256, 0, stream>>>(attn, wt2, bp, d_out,
                                      1024, 1024, flag,
                                      nullptr, nullptr, nullptr,
                                      nullptr, nullptr, nullptr);
}